// Round 5
// baseline (36.774 us; speedup 1.0000x reference)
//
#include <hip/hip_runtime.h>
#include <hip/hip_bf16.h>

// okl = log_C_kappa + kappa + mean_j log( sum_i exp(kappa*<mu_n_i,z_j> - kappa) )
//       - log(M) - log_C_zero
// M = 2048 components, J = M*n = 65536 sample columns, d = 32.
//
// Trans-pipe-free: A is pre-scaled by kappa*log2e*2^23; the MFMA C-operand
// holds (BIAS - S)*2^23 + SCHRAUDOLPH_MAGIC so c = mfma(...) is directly the
// float whose int-truncation is the IEEE bit pattern of 2^(score - S + BIAS).
// Per element: v_max (clamp), v_cvt_i32, v_add. No v_exp, no denormals.

typedef __attribute__((ext_vector_type(8))) short bf16x8;
typedef __attribute__((ext_vector_type(4))) float f32x4;
typedef __attribute__((ext_vector_type(8))) unsigned short u16x8;

#define LOG2E 1.44269504088896340736
#define LN2F 0.6931471805599453f
#define BIAS 48.0
// 127*2^23 - D, D = 471400 (mean-log-centered linear-mantissa exp2)
#define MAGIC 1064881816.0
#define CLAMPF 8388608.0f   // 2^23: result exponent floor -> 2^-126, no wrap

static __device__ __forceinline__ unsigned short f2bf(float f) {
  unsigned int u = __float_as_uint(f);
  u += 0x7FFFu + ((u >> 16) & 1u);   // round-to-nearest-even
  return (unsigned short)(u >> 16);
}

// Kernel 1: Abf = bf16(kappa*log2e*2^23 * mu / ||mu||), shape [M, 32].
__global__ __launch_bounds__(64) void vmf_prep(const float* __restrict__ mu,
                                               const float* __restrict__ kp,
                                               unsigned short* __restrict__ Abf,
                                               int M) {
  int row = blockIdx.x * 64 + threadIdx.x;
  if (row >= M) return;
  const float4* m4 = (const float4*)(mu + (size_t)row * 32);
  float4 v[8];
  float ss = 0.f;
#pragma unroll
  for (int i = 0; i < 8; ++i) {
    v[i] = m4[i];
    ss += v[i].x * v[i].x + v[i].y * v[i].y + v[i].z * v[i].z + v[i].w * v[i].w;
  }
  float sc = (float)((double)kp[0] * LOG2E * 8388608.0) / sqrtf(ss);
  u16x8 o[4];
#pragma unroll
  for (int i = 0; i < 8; ++i) {
    o[i >> 1][(i & 1) * 4 + 0] = f2bf(v[i].x * sc);
    o[i >> 1][(i & 1) * 4 + 1] = f2bf(v[i].y * sc);
    o[i >> 1][(i & 1) * 4 + 2] = f2bf(v[i].z * sc);
    o[i >> 1][(i & 1) * 4 + 3] = f2bf(v[i].w * sc);
  }
  u16x8* dst = (u16x8*)(Abf + (size_t)row * 32);
#pragma unroll
  for (int i = 0; i < 4; ++i) dst[i] = o[i];
}

// Kernel 2: block = 128 columns (8 N-tiles in registers) x 8 waves; each wave
// covers M/8 rows with a prefetched A stream. Per-column biased-exp2 sums
// combined in LDS, log'd, block-reduced to one partial per block.
__global__ __launch_bounds__(512) void vmf_main(const unsigned short* __restrict__ Abf,
                                                const float* __restrict__ z,
                                                const float* __restrict__ kp,
                                                float* __restrict__ part,
                                                int M) {
  const int lane = threadIdx.x & 63;
  const int wave = threadIdx.x >> 6;   // 0..7
  const int r = lane & 15;             // row (A) / col (B) within tile
  const int q = lane >> 4;             // k-octet quadrant
  const float ci = (float)((BIAS - (double)kp[0] * LOG2E) * 8388608.0 + MAGIC);
  const f32x4 cinit = {ci, ci, ci, ci};
  const int colbase = blockIdx.x * 128;

  // Loop-invariant B fragments (8 tiles), fp32 -> bf16 on the fly.
  bf16x8 b[8];
#pragma unroll
  for (int t = 0; t < 8; ++t) {
    const float* zp = z + (size_t)(colbase + t * 16 + r) * 32 + q * 8;
    float4 fa = *(const float4*)zp;
    float4 fb = *(const float4*)(zp + 4);
    b[t][0] = (short)f2bf(fa.x); b[t][1] = (short)f2bf(fa.y);
    b[t][2] = (short)f2bf(fa.z); b[t][3] = (short)f2bf(fa.w);
    b[t][4] = (short)f2bf(fb.x); b[t][5] = (short)f2bf(fb.y);
    b[t][6] = (short)f2bf(fb.z); b[t][7] = (short)f2bf(fb.w);
  }

  const int mchunk = M >> 3;           // rows per wave (256, power of 2)
  const unsigned short* ap = Abf + (size_t)(wave * mchunk + r) * 32 + q * 8;
  bf16x8 av = *(const bf16x8*)ap;
  float acc[8] = {0.f, 0.f, 0.f, 0.f, 0.f, 0.f, 0.f, 0.f};
  for (int m = 0; m < mchunk; m += 16) {
    const int mn = (m + 16) & (mchunk - 1);          // wraparound: branchless
    bf16x8 nxt = *(const bf16x8*)(ap + (size_t)mn * 32);
#pragma unroll
    for (int t = 0; t < 8; ++t) {
      f32x4 c = __builtin_amdgcn_mfma_f32_16x16x32_bf16(av, b[t], cinit, 0, 0, 0);
#pragma unroll
      for (int e = 0; e < 4; ++e) {
        float cf = fmaxf(c[e], CLAMPF);
        acc[t] += __int_as_float((int)cf);   // Schraudolph exp2
      }
    }
    av = nxt;
  }

  // Sum the 4 row-quadrants per column (lanes l, l^16, l^32, l^48 share col).
#pragma unroll
  for (int t = 0; t < 8; ++t) {
    acc[t] += __shfl_xor(acc[t], 16);
    acc[t] += __shfl_xor(acc[t], 32);
  }
  // Lane l owns block-cols (l>>4)*16+(l&15) (tiles 0-3) and +64 (tiles 4-7).
  float vlo = (q == 0) ? acc[0] : (q == 1) ? acc[1] : (q == 2) ? acc[2] : acc[3];
  float vhi = (q == 0) ? acc[4] : (q == 1) ? acc[5] : (q == 2) ? acc[6] : acc[7];

  __shared__ float rlo[8][64];
  __shared__ float rhi[8][64];
  rlo[wave][lane] = vlo;
  rhi[wave][lane] = vhi;
  __syncthreads();

  if (wave == 0) {
    float slo = 0.f, shi = 0.f;
#pragma unroll
    for (int w = 0; w < 8; ++w) { slo += rlo[w][lane]; shi += rhi[w][lane]; }
    slo = fmaxf(slo, 1e-38f);
    shi = fmaxf(shi, 1e-38f);
    float t = __logf(slo) + __logf(shi);   // 2 columns' t_j for this lane
    t += __shfl_xor(t, 1);  t += __shfl_xor(t, 2);
    t += __shfl_xor(t, 4);  t += __shfl_xor(t, 8);
    t += __shfl_xor(t, 16); t += __shfl_xor(t, 32);
    if (lane == 0) part[blockIdx.x] = t;   // sum over this block's 128 columns
  }
}

// Kernel 3: reduce per-block partials, apply constants (incl. -BIAS*ln2).
__global__ __launch_bounds__(256) void vmf_final(const float* __restrict__ part, int n,
                                                 const float* __restrict__ kp,
                                                 const float* __restrict__ lck,
                                                 const float* __restrict__ lc0,
                                                 float* __restrict__ out,
                                                 int M, int J) {
  __shared__ float red[256];
  float s = 0.f;
  for (int i = threadIdx.x; i < n; i += 256) s += part[i];
  red[threadIdx.x] = s;
  __syncthreads();
  for (int off = 128; off > 0; off >>= 1) {
    if (threadIdx.x < off) red[threadIdx.x] += red[threadIdx.x + off];
    __syncthreads();
  }
  if (threadIdx.x == 0) {
    float tbar = red[0] / (float)J - (float)BIAS * LN2F;
    out[0] = lck[0] + kp[0] + tbar - logf((float)M) - lc0[0];
  }
}

extern "C" void kernel_launch(void* const* d_in, const int* in_sizes, int n_in,
                              void* d_out, int out_size, void* d_ws, size_t ws_size,
                              hipStream_t stream) {
  const float* mu  = (const float*)d_in[0];
  const float* z   = (const float*)d_in[1];
  const float* kp  = (const float*)d_in[2];
  const float* lck = (const float*)d_in[3];
  const float* lc0 = (const float*)d_in[4];
  const int M = in_sizes[0] / 32;   // 2048
  const int J = in_sizes[1] / 32;   // 65536 (= M * n_samples)

  char* ws = (char*)d_ws;
  unsigned short* Abf = (unsigned short*)ws;                 // M*32*2 = 128 KB
  size_t abytes = ((size_t)M * 32 * 2 + 255) & ~(size_t)255;
  float* part = (float*)(ws + abytes);                       // nblk floats

  vmf_prep<<<(M + 63) / 64, 64, 0, stream>>>(mu, kp, Abf, M);
  const int nblk = J / 128;  // 512 blocks, 8 waves each
  vmf_main<<<nblk, 512, 0, stream>>>(Abf, z, kp, part, M);
  vmf_final<<<1, 256, 0, stream>>>(part, nblk, kp, lck, lc0, (float*)d_out, M, J);
}